// Round 9
// baseline (420.792 us; speedup 1.0000x reference)
//
#include <hip/hip_runtime.h>

#define NN 100000
#define D 128
#define CHUNK 4096
#define BCSTRIDE 392
#define AGG_BLOCKS 1024

typedef __attribute__((ext_vector_type(8))) short short8;
typedef __attribute__((ext_vector_type(8))) unsigned short ushort8;
typedef __attribute__((ext_vector_type(4))) float f32x4;

__device__ __forceinline__ float4 ld4(const float* p) { return *(const float4*)p; }

__device__ __forceinline__ unsigned short f2bf(float f) {
    unsigned int u = __float_as_uint(f);
    unsigned int r = u + 0x7fffu + ((u >> 16) & 1u);   // RNE
    return (unsigned short)(r >> 16);
}
__device__ __forceinline__ float bf2f(unsigned short h) {
    return __uint_as_float(((unsigned int)h) << 16);
}
__device__ __forceinline__ float blo(unsigned int u) { return __uint_as_float(u << 16); }
__device__ __forceinline__ float bhi(unsigned int u) { return __uint_as_float(u & 0xffff0000u); }

// LDS layout: 64 rows x 128 uints, 16B-unit index XOR'd with row&7 (R6-validated:
// all GEMM-phase LDS accesses at the b128 8-cycle floor).
__device__ __forceinline__ int swz(int r, int c) {
    return r * 128 + ((((c >> 2) ^ (r & 7)) << 2) | (c & 3));
}

// 8-wave block-cooperative GEMM (R8-validated): wave wv computes output cols
// [wv*16, wv*16+16) for all 64 rows; 512-thr blocks -> 32 waves/CU.
__device__ __forceinline__ void coop_gemm8(
    const unsigned int* uT,
    const unsigned short* __restrict__ Whi, const unsigned short* __restrict__ Wlo,
    int wv, int lane, int lr, int q, f32x4 acc[4])
{
    #pragma unroll
    for (int ks = 0; ks < 4; ++ks) {
        short8 ahi[4], alo[4];
        #pragma unroll
        for (int m = 0; m < 4; ++m) {
            const int row = m * 16 + lr;
            const int cb  = ks * 32 + q * 8;
            const uint4 a0 = *(const uint4*)&uT[swz(row, cb)];
            const uint4 a1 = *(const uint4*)&uT[swz(row, cb + 4)];
            const unsigned int w[8] = {a0.x, a0.y, a0.z, a0.w, a1.x, a1.y, a1.z, a1.w};
            #pragma unroll
            for (int j = 0; j < 8; ++j) {
                ahi[m][j] = (short)(w[j] >> 16);
                alo[m][j] = (short)(w[j] & 0xffffu);
            }
        }
        const int base = ((wv * 4 + ks) * 64 + lane) * 8;
        const short8 bhi8 = *(const short8*)&Whi[base];
        const short8 blo8 = *(const short8*)&Wlo[base];
        #pragma unroll
        for (int m = 0; m < 4; ++m) {
            acc[m] = __builtin_amdgcn_mfma_f32_16x16x32_bf16(alo[m], bhi8, acc[m], 0, 0, 0);
            acc[m] = __builtin_amdgcn_mfma_f32_16x16x32_bf16(ahi[m], blo8, acc[m], 0, 0, 0);
            acc[m] = __builtin_amdgcn_mfma_f32_16x16x32_bf16(ahi[m], bhi8, acc[m], 0, 0, 0);
        }
    }
}

// ---------------- gemm_in body (8-wave), parameterized by block id ----------------
__device__ __forceinline__ void gemm_in_body(
    unsigned int* uT, int bid,
    const float* __restrict__ A1,
    const unsigned short* __restrict__ Whi, const unsigned short* __restrict__ Wlo,
    const float* __restrict__ bias,
    unsigned short* __restrict__ out_hi, unsigned short* __restrict__ out_lo, int N)
{
    const int t    = threadIdx.x;
    const int wv   = t >> 6;
    const int lane = t & 63;
    const int lr   = lane & 15;
    const int q    = lane >> 4;
    const int rE   = wv * 8 + (lane >> 3);   // row in tile (16 elems/thread)
    const int cE   = (lane & 7) * 16;        // col base
    const int rowE = bid * 64 + rE;

    // phase 1: pack split-bf16(x) into uT
    {
        float v[16];
        if (rowE < N) {
            const int off = rowE * D + cE;
            #pragma unroll
            for (int k = 0; k < 4; ++k) {
                const float4 x = ld4(&A1[off + k * 4]);
                v[k * 4 + 0] = x.x; v[k * 4 + 1] = x.y; v[k * 4 + 2] = x.z; v[k * 4 + 3] = x.w;
            }
        } else {
            #pragma unroll
            for (int j = 0; j < 16; ++j) v[j] = 0.f;
        }
        #pragma unroll
        for (int k = 0; k < 4; ++k) {
            unsigned int pk[4];
            #pragma unroll
            for (int j = 0; j < 4; ++j) {
                const float f = v[k * 4 + j];
                const unsigned int hi = f2bf(f);
                pk[j] = (hi << 16) | f2bf(f - bf2f((unsigned short)hi));
            }
            *(uint4*)&uT[swz(rE, cE + k * 4)] = make_uint4(pk[0], pk[1], pk[2], pk[3]);
        }
    }
    __syncthreads();

    f32x4 acc[4];
    #pragma unroll
    for (int m = 0; m < 4; ++m) acc[m] = (f32x4){0.f, 0.f, 0.f, 0.f};
    coop_gemm8(uT, Whi, Wlo, wv, lane, lr, q, acc);
    __syncthreads();   // all A-reads done before C overwrite

    {
        const float b = bias[wv * 16 + lr];
        #pragma unroll
        for (int m = 0; m < 4; ++m)
            #pragma unroll
            for (int r = 0; r < 4; ++r)
                uT[swz(m * 16 + q * 4 + r, wv * 16 + lr)] = __float_as_uint(acc[m][r] + b);
    }
    __syncthreads();

    if (rowE < N) {
        const int off = rowE * D + cE;
        unsigned int w[16];
        #pragma unroll
        for (int k = 0; k < 4; ++k) {
            const uint4 a = *(const uint4*)&uT[swz(rE, cE + k * 4)];
            w[k * 4 + 0] = a.x; w[k * 4 + 1] = a.y; w[k * 4 + 2] = a.z; w[k * 4 + 3] = a.w;
        }
        #pragma unroll
        for (int h8 = 0; h8 < 2; ++h8) {
            ushort8 oh, ol;
            #pragma unroll
            for (int j = 0; j < 8; ++j) {
                const float o = __uint_as_float(w[h8 * 8 + j]);
                const unsigned short h = f2bf(o);
                oh[j] = h;
                ol[j] = f2bf(o - bf2f(h));
            }
            *(ushort8*)&out_hi[off + h8 * 8] = oh;
            *(ushort8*)&out_lo[off + h8 * 8] = ol;
        }
    }
}

// ---------------- fused setup: 5x W prepack + emb prepack + binTotal zero ----------------
__global__ __launch_bounds__(256) void setup_all(
    const float* __restrict__ W0, const float* __restrict__ W1,
    const float* __restrict__ W2, const float* __restrict__ W3,
    const float* __restrict__ W4, unsigned short* __restrict__ wp,
    const float* __restrict__ emb, unsigned int* __restrict__ embp,
    int* __restrict__ binTotal)
{
    const int T = blockIdx.x * 256 + threadIdx.x;
    if (T < 5 * D * D) {
        const int w = T / (D * D);
        const int t = T % (D * D);
        const float* W = (w == 0) ? W0 : (w == 1) ? W1 : (w == 2) ? W2 : (w == 3) ? W3 : W4;
        const int j  = t & 7;
        const int L  = (t >> 3) & 63;
        const int ks = (t >> 9) & 3;
        const int nt = t >> 11;
        const float v = W[(ks * 32 + (L >> 4) * 8 + j) * D + nt * 16 + (L & 15)];
        const unsigned short h = f2bf(v);
        unsigned short* hi = wp + (size_t)w * 2 * D * D;
        hi[t] = h;
        hi[D * D + t] = f2bf(v - bf2f(h));
    } else if (T < 5 * D * D + 6400) {
        const int i = T - 5 * D * D;
        embp[i] = (unsigned int)f2bf(emb[i * 2]) | ((unsigned int)f2bf(emb[i * 2 + 1]) << 16);
    } else if (T < 5 * D * D + 6400 + BCSTRIDE) {
        binTotal[T - 5 * D * D - 6400] = 0;
    }
}

// ---------------- K1: bin_count || gemm_in slice A (512 thr) ----------------
__global__ __launch_bounds__(512, 8) void fuse_count_gemm(
    const int* __restrict__ dst, int* __restrict__ blkcnt,
    int* __restrict__ binTotal, int E, int nbins, int csrB,
    const float* __restrict__ A1,
    const unsigned short* __restrict__ Whi, const unsigned short* __restrict__ Wlo,
    const float* __restrict__ bias,
    unsigned short* __restrict__ out_hi, unsigned short* __restrict__ out_lo,
    int N, int gemmBase)
{
    __shared__ __align__(16) unsigned int uT[64 * 128];   // 32 KB; CSR path aliases
    if ((int)blockIdx.x < csrB) {
        int* hist = (int*)uT;   // nbins ints
        const int t = threadIdx.x;
        const int i = blockIdx.x;
        for (int k = t; k < nbins; k += 512) hist[k] = 0;
        __syncthreads();
        const int e0 = i * CHUNK;
        const int e1 = min(E, e0 + CHUNK);
        for (int e = e0 + t; e < e1; e += 512) atomicAdd(&hist[dst[e] >> 8], 1);
        __syncthreads();
        for (int k = t; k < nbins; k += 512) {
            const int c = hist[k];
            blkcnt[i * BCSTRIDE + k] = c;
            if (c) atomicAdd(&binTotal[k], c);
        }
    } else {
        gemm_in_body(uT, blockIdx.x - csrB + gemmBase, A1, Whi, Wlo, bias, out_hi, out_lo, N);
    }
}

__global__ __launch_bounds__(512) void bin_scan(
    const int* __restrict__ binTotal, int* __restrict__ binStart,
    int* __restrict__ binCursor, int nbins)
{
    __shared__ int s[512];
    const int t = threadIdx.x;
    const int v = (t < nbins) ? binTotal[t] : 0;
    s[t] = v;
    __syncthreads();
    for (int off = 1; off < 512; off <<= 1) {
        const int x = (t >= off) ? s[t - off] : 0;
        __syncthreads();
        s[t] += x;
        __syncthreads();
    }
    if (t < nbins) { binStart[t] = s[t] - v; binCursor[t] = s[t] - v; }
    if (t == 0)    binStart[nbins] = s[511];
}

// ---------------- K2: bin_scatter || gemm_in slice B (512 thr) ----------------
__global__ __launch_bounds__(512, 8) void fuse_scatter_gemm(
    const int* __restrict__ src, const int* __restrict__ dst,
    const int* __restrict__ attr, const int* __restrict__ blkcnt,
    int* __restrict__ binCursor, int2* __restrict__ binned, int E, int nbins, int csrB,
    const float* __restrict__ A1,
    const unsigned short* __restrict__ Whi, const unsigned short* __restrict__ Wlo,
    const float* __restrict__ bias,
    unsigned short* __restrict__ out_hi, unsigned short* __restrict__ out_lo,
    int N, int gemmBase)
{
    __shared__ __align__(16) unsigned int uT[64 * 128];
    if ((int)blockIdx.x < csrB) {
        int* cur = (int*)uT;   // nbins ints
        const int t = threadIdx.x;
        const int i = blockIdx.x;
        for (int k = t; k < nbins; k += 512) {
            const int c = blkcnt[i * BCSTRIDE + k];
            if (c) cur[k] = atomicAdd(&binCursor[k], c);
        }
        __syncthreads();
        const int e0 = i * CHUNK;
        const int e1 = min(E, e0 + CHUNK);
        for (int e = e0 + t; e < e1; e += 512) {
            const int d = dst[e];
            const int p = atomicAdd(&cur[d >> 8], 1);
            binned[p] = make_int2(src[e] | (attr[e] << 20), d);
        }
    } else {
        gemm_in_body(uT, blockIdx.x - csrB + gemmBase, A1, Whi, Wlo, bias, out_hi, out_lo, N);
    }
}

// ---------------- K3: bin_build || gemm_in slice C (512 thr) ----------------
__global__ __launch_bounds__(512, 8) void fuse_build_gemm(
    const int2* __restrict__ binned, const int* __restrict__ binStart,
    int* __restrict__ rowptr, int* __restrict__ epack, int csrB,
    const float* __restrict__ A1,
    const unsigned short* __restrict__ Whi, const unsigned short* __restrict__ Wlo,
    const float* __restrict__ bias,
    unsigned short* __restrict__ out_hi, unsigned short* __restrict__ out_lo,
    int N, int gemmBase)
{
    __shared__ __align__(16) unsigned int uT[64 * 128];
    if ((int)blockIdx.x < csrB) {
        int* hist = (int*)uT;          // 256
        int* scn  = (int*)uT + 256;    // 256
        int* curn = (int*)uT + 512;    // 256
        const int t = threadIdx.x;
        const int b = blockIdx.x;
        if (t < 256) hist[t] = 0;
        __syncthreads();
        const int ebeg = binStart[b];
        const int eend = binStart[b + 1];
        for (int e = ebeg + t; e < eend; e += 512) atomicAdd(&hist[binned[e].y & 255], 1);
        __syncthreads();
        if (t < 256) scn[t] = hist[t];
        __syncthreads();
        for (int off = 1; off < 256; off <<= 1) {
            int x = 0;
            if (t < 256 && t >= off) x = scn[t - off];
            __syncthreads();
            if (t < 256) scn[t] += x;
            __syncthreads();
        }
        if (t < 256) {
            const int node = b * 256 + t;
            if (node < N) rowptr[node] = ebeg + scn[t];
            curn[t] = ebeg + scn[t] - hist[t];
        }
        __syncthreads();
        for (int e = ebeg + t; e < eend; e += 512) {
            const int2 v = binned[e];
            const int p = atomicAdd(&curn[v.y & 255], 1);
            epack[p] = v.x;
        }
    } else {
        gemm_in_body(uT, blockIdx.x - csrB + gemmBase, A1, Whi, Wlo, bias, out_hi, out_lo, N);
    }
}

// ---------------- fused GINE MLP (8-wave coop, + optional fused output projection) ----------------
// h_hi/h_lo/out_hi/out_lo NOT __restrict__: <false> runs in-place (out==h); the
// epilogue reloads hh/ll (L2-hot) right before overwriting.
template<bool LAST>
__global__ __launch_bounds__(512, 8) void mlp_fused(
    const float* __restrict__ agg,
    const unsigned short* h_hi, const unsigned short* h_lo,
    const unsigned short* __restrict__ W1hi, const unsigned short* __restrict__ W1lo,
    const float* __restrict__ b1,
    const unsigned short* __restrict__ W2hi, const unsigned short* __restrict__ W2lo,
    const float* __restrict__ b2,
    unsigned short* out_hi, unsigned short* out_lo,
    const float* __restrict__ Wout, const float* __restrict__ bout,
    float* __restrict__ outv, int N)
{
    __shared__ __align__(16) unsigned int uT[64 * 128];   // 32 KB -> 4 blocks/CU @ 8 waves
    const int t    = threadIdx.x;
    const int wv   = t >> 6;
    const int lane = t & 63;
    const int lr   = lane & 15;
    const int q    = lane >> 4;
    const int rE   = wv * 8 + (lane >> 3);
    const int cE   = (lane & 7) * 16;
    const int rowE = blockIdx.x * 64 + rE;

    // phase 1: pack split-bf16(agg + h_hi + h_lo) into uT
    {
        float v[16];
        if (rowE < N) {
            const int off = rowE * D + cE;
            #pragma unroll
            for (int k = 0; k < 4; ++k) {
                const float4 x = ld4(&agg[off + k * 4]);
                v[k * 4 + 0] = x.x; v[k * 4 + 1] = x.y; v[k * 4 + 2] = x.z; v[k * 4 + 3] = x.w;
            }
            #pragma unroll
            for (int h8 = 0; h8 < 2; ++h8) {
                const ushort8 hh = *(const ushort8*)&h_hi[off + h8 * 8];
                const ushort8 ll = *(const ushort8*)&h_lo[off + h8 * 8];
                #pragma unroll
                for (int j = 0; j < 8; ++j) v[h8 * 8 + j] += bf2f(hh[j]) + bf2f(ll[j]);
            }
        } else {
            #pragma unroll
            for (int j = 0; j < 16; ++j) v[j] = 0.f;
        }
        #pragma unroll
        for (int k = 0; k < 4; ++k) {
            unsigned int pk[4];
            #pragma unroll
            for (int j = 0; j < 4; ++j) {
                const float f = v[k * 4 + j];
                const unsigned int hi = f2bf(f);
                pk[j] = (hi << 16) | f2bf(f - bf2f((unsigned short)hi));
            }
            *(uint4*)&uT[swz(rE, cE + k * 4)] = make_uint4(pk[0], pk[1], pk[2], pk[3]);
        }
    }
    __syncthreads();

    // GEMM1
    f32x4 acc[4];
    #pragma unroll
    for (int m = 0; m < 4; ++m) acc[m] = (f32x4){0.f, 0.f, 0.f, 0.f};
    coop_gemm8(uT, W1hi, W1lo, wv, lane, lr, q, acc);
    __syncthreads();   // A-reads done before mid overwrite

    // mid = relu(acc + b1) -> packed split-bf16 in uT
    {
        const float b = b1[wv * 16 + lr];
        #pragma unroll
        for (int m = 0; m < 4; ++m)
            #pragma unroll
            for (int r = 0; r < 4; ++r) {
                const float o = fmaxf(acc[m][r] + b, 0.f);
                const unsigned int hi = f2bf(o);
                const unsigned int lo = f2bf(o - bf2f((unsigned short)hi));
                uT[swz(m * 16 + q * 4 + r, wv * 16 + lr)] = (hi << 16) | lo;
            }
    }
    __syncthreads();

    // GEMM2
    f32x4 acc2[4];
    #pragma unroll
    for (int m = 0; m < 4; ++m) acc2[m] = (f32x4){0.f, 0.f, 0.f, 0.f};
    coop_gemm8(uT, W2hi, W2lo, wv, lane, lr, q, acc2);
    __syncthreads();   // mid-reads done before C2 overwrite

    {
        const float b = b2[wv * 16 + lr];
        #pragma unroll
        for (int m = 0; m < 4; ++m)
            #pragma unroll
            for (int r = 0; r < 4; ++r)
                uT[swz(m * 16 + q * 4 + r, wv * 16 + lr)] = __float_as_uint(acc2[m][r] + b);
    }
    __syncthreads();

    // epilogue: 16 elems per thread on row rE
    if (LAST) {
        float accv = 0.f;
        if (rowE < N) {
            const int off = rowE * D + cE;
            unsigned int w[16];
            #pragma unroll
            for (int k = 0; k < 4; ++k) {
                const uint4 a = *(const uint4*)&uT[swz(rE, cE + k * 4)];
                w[k * 4 + 0] = a.x; w[k * 4 + 1] = a.y; w[k * 4 + 2] = a.z; w[k * 4 + 3] = a.w;
            }
            #pragma unroll
            for (int h8 = 0; h8 < 2; ++h8) {
                const ushort8 hh = *(const ushort8*)&h_hi[off + h8 * 8];
                const ushort8 ll = *(const ushort8*)&h_lo[off + h8 * 8];
                const float4 w0 = ld4(&Wout[cE + h8 * 8]);
                const float4 w1 = ld4(&Wout[cE + h8 * 8 + 4]);
                float o[8];
                #pragma unroll
                for (int j = 0; j < 8; ++j)
                    o[j] = fmaxf(__uint_as_float(w[h8 * 8 + j]) + bf2f(hh[j]) + bf2f(ll[j]), 0.f);
                accv += o[0] * w0.x + o[1] * w0.y + o[2] * w0.z + o[3] * w0.w;
                accv += o[4] * w1.x + o[5] * w1.y + o[6] * w1.z + o[7] * w1.w;
            }
        }
        accv += __shfl_xor(accv, 1);
        accv += __shfl_xor(accv, 2);
        accv += __shfl_xor(accv, 4);
        if ((lane & 7) == 0 && rowE < N) outv[rowE] = accv + bout[0];
    } else if (rowE < N) {
        const int off = rowE * D + cE;
        unsigned int w[16];
        #pragma unroll
        for (int k = 0; k < 4; ++k) {
            const uint4 a = *(const uint4*)&uT[swz(rE, cE + k * 4)];
            w[k * 4 + 0] = a.x; w[k * 4 + 1] = a.y; w[k * 4 + 2] = a.z; w[k * 4 + 3] = a.w;
        }
        #pragma unroll
        for (int h8 = 0; h8 < 2; ++h8) {
            const ushort8 hh = *(const ushort8*)&h_hi[off + h8 * 8];
            const ushort8 ll = *(const ushort8*)&h_lo[off + h8 * 8];
            ushort8 oh, ol;
            #pragma unroll
            for (int j = 0; j < 8; ++j) {
                const float o = fmaxf(__uint_as_float(w[h8 * 8 + j]) + bf2f(hh[j]) + bf2f(ll[j]), 0.f);
                const unsigned short h = f2bf(o);
                oh[j] = h;
                ol[j] = f2bf(o - bf2f(h));
            }
            *(ushort8*)&out_hi[off + h8 * 8] = oh;
            *(ushort8*)&out_lo[off + h8 * 8] = ol;
        }
    }
}

// ---------------- CSR aggregate: paired edges, uint2/lane (R9) ----------------
// Lanes 0-31 process edge j, lanes 32-63 edge j+1; each lane loads 8B covering
// dims 4k..4k+3. Halves combined at the end via shfl_xor(32). Same bytes as the
// per-edge version with HALF the VMEM/LDS instructions and loop iterations.
__global__ __launch_bounds__(512) void aggregate(
    const unsigned int* __restrict__ hu,
    const int* __restrict__ rowptr, const int* __restrict__ epack,
    const unsigned int* __restrict__ embp, float* __restrict__ agg, int N)
{
    __shared__ unsigned int semb[100 * 64];   // 25.6 KB packed bf16 emb table
    const int t = threadIdx.x;
    for (int i = t; i < 100 * 64; i += 512) semb[i] = embp[i];
    __syncthreads();

    const int wv   = t >> 6;    // 0..7
    const int lane = t & 63;
    const int half = lane >> 5; // 0: even edge, 1: odd edge
    const int k    = lane & 31; // uint2 index within row (dims 4k..4k+3)

    const uint2* hu2   = (const uint2*)hu;
    const uint2* semb2 = (const uint2*)semb;

    for (int node = blockIdx.x * 8 + wv; node < N; node += AGG_BLOCKS * 8) {
        int start = (node == 0) ? 0 : rowptr[node - 1];
        int end   = rowptr[node];
        start = __builtin_amdgcn_readfirstlane(start);
        end   = __builtin_amdgcn_readfirstlane(end);

        float a0 = 0.f, a1 = 0.f, a2 = 0.f, a3 = 0.f;
        int j = start;

        // align j to 4 (singles: lanes 0-31 only)
        for (; j < end && (j & 3); ++j) {
            const int p = __builtin_amdgcn_readfirstlane(epack[j]);
            if (!half) {
                const uint2 u = hu2[(p & 0xFFFFF) * 32 + k];
                const uint2 v = semb2[(p >> 20) * 32 + k];
                a0 += fmaxf(blo(u.x) + blo(v.x), 0.f);
                a1 += fmaxf(bhi(u.x) + bhi(v.x), 0.f);
                a2 += fmaxf(blo(u.y) + blo(v.y), 0.f);
                a3 += fmaxf(bhi(u.y) + bhi(v.y), 0.f);
            }
        }

        // main: 4 edges (2 pairs) per iteration
        for (; j + 3 < end; j += 4) {
            const int4 pk = *(const int4*)&epack[j];
            const int pA0 = __builtin_amdgcn_readfirstlane(pk.x);
            const int pB0 = __builtin_amdgcn_readfirstlane(pk.y);
            const int pA1 = __builtin_amdgcn_readfirstlane(pk.z);
            const int pB1 = __builtin_amdgcn_readfirstlane(pk.w);
            const int p0 = half ? pB0 : pA0;
            const int p1 = half ? pB1 : pA1;
            const uint2 u0 = hu2[(p0 & 0xFFFFF) * 32 + k];
            const uint2 u1 = hu2[(p1 & 0xFFFFF) * 32 + k];
            const uint2 v0 = semb2[(p0 >> 20) * 32 + k];
            const uint2 v1 = semb2[(p1 >> 20) * 32 + k];
            a0 += fmaxf(blo(u0.x) + blo(v0.x), 0.f);
            a1 += fmaxf(bhi(u0.x) + bhi(v0.x), 0.f);
            a2 += fmaxf(blo(u0.y) + blo(v0.y), 0.f);
            a3 += fmaxf(bhi(u0.y) + bhi(v0.y), 0.f);
            a0 += fmaxf(blo(u1.x) + blo(v1.x), 0.f);
            a1 += fmaxf(bhi(u1.x) + bhi(v1.x), 0.f);
            a2 += fmaxf(blo(u1.y) + blo(v1.y), 0.f);
            a3 += fmaxf(bhi(u1.y) + bhi(v1.y), 0.f);
        }

        // pair tail
        if (j + 1 < end) {
            const int2 pk = *(const int2*)&epack[j];
            const int pA = __builtin_amdgcn_readfirstlane(pk.x);
            const int pB = __builtin_amdgcn_readfirstlane(pk.y);
            const int p = half ? pB : pA;
            const uint2 u = hu2[(p & 0xFFFFF) * 32 + k];
            const uint2 v = semb2[(p >> 20) * 32 + k];
            a0 += fmaxf(blo(u.x) + blo(v.x), 0.f);
            a1 += fmaxf(bhi(u.x) + bhi(v.x), 0.f);
            a2 += fmaxf(blo(u.y) + blo(v.y), 0.f);
            a3 += fmaxf(bhi(u.y) + bhi(v.y), 0.f);
            j += 2;
        }
        // single tail
        if (j < end) {
            const int p = __builtin_amdgcn_readfirstlane(epack[j]);
            if (!half) {
                const uint2 u = hu2[(p & 0xFFFFF) * 32 + k];
                const uint2 v = semb2[(p >> 20) * 32 + k];
                a0 += fmaxf(blo(u.x) + blo(v.x), 0.f);
                a1 += fmaxf(bhi(u.x) + bhi(v.x), 0.f);
                a2 += fmaxf(blo(u.y) + blo(v.y), 0.f);
                a3 += fmaxf(bhi(u.y) + bhi(v.y), 0.f);
            }
        }

        // combine halves; lanes 0-31 write the full row as float4 (coalesced 512B)
        a0 += __shfl_xor(a0, 32);
        a1 += __shfl_xor(a1, 32);
        a2 += __shfl_xor(a2, 32);
        a3 += __shfl_xor(a3, 32);
        if (!half)
            *(float4*)&agg[node * D + k * 4] = make_float4(a0, a1, a2, a3);
    }
}

extern "C" void kernel_launch(void* const* d_in, const int* in_sizes, int n_in,
                              void* d_out, int out_size, void* d_ws, size_t ws_size,
                              hipStream_t stream)
{
    const float* x     = (const float*)d_in[0];
    const int*   ei    = (const int*)  d_in[1];
    const int*   attr  = (const int*)  d_in[2];
    const float* emb   = (const float*)d_in[3];
    const float* Win   = (const float*)d_in[4];
    const float* b_in  = (const float*)d_in[5];
    const float* W1_0  = (const float*)d_in[6];
    const float* b1_0  = (const float*)d_in[7];
    const float* W2_0  = (const float*)d_in[8];
    const float* b2_0  = (const float*)d_in[9];
    const float* W1_1  = (const float*)d_in[10];
    const float* b1_1  = (const float*)d_in[11];
    const float* W2_1  = (const float*)d_in[12];
    const float* b2_1  = (const float*)d_in[13];
    const float* Wout  = (const float*)d_in[14];
    const float* b_out = (const float*)d_in[15];
    float* out = (float*)d_out;

    const int N = NN;
    const int E = in_sizes[2];
    const int* srcp = ei;
    const int* dstp = ei + E;
    const int nbins = (N + 255) >> 8;
    const int eblocks = (E + CHUNK - 1) / CHUNK;

    // persistent workspace
    unsigned short* h_hi = (unsigned short*)d_ws;        // N*D ushort
    unsigned short* h_lo = h_hi + (size_t)N * D;         // N*D ushort
    float* agg    = (float*)(h_lo + (size_t)N * D);      // N*D float
    int*   rowptr = (int*)(agg + (size_t)N * D);         // N
    int*   epack  = rowptr + N;                          // E
    unsigned short* wp = (unsigned short*)(epack + E);   // 5*2*D*D
    unsigned short* Whi[5], *Wlo[5];
    for (int i = 0; i < 5; ++i) {
        Whi[i] = wp + (size_t)i * 2 * D * D;
        Wlo[i] = Whi[i] + D * D;
    }
    unsigned int* embp = (unsigned int*)(wp + 5 * 2 * D * D);  // 100*64 uint
    // CSR-build scratch aliased into agg (dead until first aggregate)
    int2* binned    = (int2*)agg;                         // E
    int*  blkcnt    = (int*)(binned + E);                 // eblocks*BCSTRIDE
    int*  binTotal  = blkcnt + eblocks * BCSTRIDE;        // nbins
    int*  binStart  = binTotal + BCSTRIDE;                // nbins+1
    int*  binCursor = binStart + BCSTRIDE;                // nbins

    const int fgrid = (N + 63) / 64;                      // 1563 tiles
    const int sgrid = (5 * D * D + 6400 + BCSTRIDE + 255) / 256;

    // gemm_in tile slices overlapped with CSR stages
    const int G1 = 200;
    const int G2 = 700;
    const int G3 = fgrid - G1 - G2;                       // 663

    // ---- fused setup: W/emb prepack + binTotal zero ----
    setup_all<<<sgrid, dim3(256), 0, stream>>>(Win, W1_0, W2_0, W1_1, W2_1, wp, emb, embp, binTotal);

    // ---- CSR build overlapped with gemm_in slices (512-thr blocks) ----
    fuse_count_gemm<<<eblocks + G1, dim3(512), 0, stream>>>(
        dstp, blkcnt, binTotal, E, nbins, eblocks,
        x, Whi[0], Wlo[0], b_in, h_hi, h_lo, N, 0);
    bin_scan<<<1, 512, 0, stream>>>(binTotal, binStart, binCursor, nbins);
    fuse_scatter_gemm<<<eblocks + G2, dim3(512), 0, stream>>>(
        srcp, dstp, attr, blkcnt, binCursor, binned, E, nbins, eblocks,
        x, Whi[0], Wlo[0], b_in, h_hi, h_lo, N, G1);
    fuse_build_gemm<<<nbins + G3, dim3(512), 0, stream>>>(
        binned, binStart, rowptr, epack, nbins,
        x, Whi[0], Wlo[0], b_in, h_hi, h_lo, N, G1 + G2);

    // ---- layer 0 ----
    aggregate<<<AGG_BLOCKS, dim3(512), 0, stream>>>(
        (const unsigned int*)h_hi, rowptr, epack, embp, agg, N);
    mlp_fused<false><<<fgrid, dim3(512), 0, stream>>>(
        agg, h_hi, h_lo, Whi[1], Wlo[1], b1_0, Whi[2], Wlo[2], b2_0,
        h_hi, h_lo, nullptr, nullptr, nullptr, N);

    // ---- layer 1 + fused output projection ----
    aggregate<<<AGG_BLOCKS, dim3(512), 0, stream>>>(
        (const unsigned int*)h_hi, rowptr, epack, embp, agg, N);
    mlp_fused<true><<<fgrid, dim3(512), 0, stream>>>(
        agg, h_hi, h_lo, Whi[3], Wlo[3], b1_1, Whi[4], Wlo[4], b2_1,
        nullptr, nullptr, Wout, b_out, out, N);
}

// Round 10
// 397.347 us; speedup vs baseline: 1.0590x; 1.0590x over previous
//
#include <hip/hip_runtime.h>

#define NN 100000
#define D 128
#define CHUNK 4096
#define BCSTRIDE 392

typedef __attribute__((ext_vector_type(8))) short short8;
typedef __attribute__((ext_vector_type(8))) unsigned short ushort8;
typedef __attribute__((ext_vector_type(4))) float f32x4;

__device__ __forceinline__ float4 ld4(const float* p) { return *(const float4*)p; }

__device__ __forceinline__ unsigned short f2bf(float f) {
    unsigned int u = __float_as_uint(f);
    unsigned int r = u + 0x7fffu + ((u >> 16) & 1u);   // RNE
    return (unsigned short)(r >> 16);
}
__device__ __forceinline__ float bf2f(unsigned short h) {
    return __uint_as_float(((unsigned int)h) << 16);
}
__device__ __forceinline__ float blo(unsigned int u) { return __uint_as_float(u << 16); }
__device__ __forceinline__ float bhi(unsigned int u) { return __uint_as_float(u & 0xffff0000u); }

// LDS layout: 64 rows x 128 uints, 16B-unit index XOR'd with row&7 (R6-validated).
__device__ __forceinline__ int swz(int r, int c) {
    return r * 128 + ((((c >> 2) ^ (r & 7)) << 2) | (c & 3));
}

// 8-wave block-cooperative GEMM (R8-validated): wave wv computes output cols
// [wv*16, wv*16+16) for all 64 rows; 512-thr blocks -> 32 waves/CU.
__device__ __forceinline__ void coop_gemm8(
    const unsigned int* uT,
    const unsigned short* __restrict__ Whi, const unsigned short* __restrict__ Wlo,
    int wv, int lane, int lr, int q, f32x4 acc[4])
{
    #pragma unroll
    for (int ks = 0; ks < 4; ++ks) {
        short8 ahi[4], alo[4];
        #pragma unroll
        for (int m = 0; m < 4; ++m) {
            const int row = m * 16 + lr;
            const int cb  = ks * 32 + q * 8;
            const uint4 a0 = *(const uint4*)&uT[swz(row, cb)];
            const uint4 a1 = *(const uint4*)&uT[swz(row, cb + 4)];
            const unsigned int w[8] = {a0.x, a0.y, a0.z, a0.w, a1.x, a1.y, a1.z, a1.w};
            #pragma unroll
            for (int j = 0; j < 8; ++j) {
                ahi[m][j] = (short)(w[j] >> 16);
                alo[m][j] = (short)(w[j] & 0xffffu);
            }
        }
        const int base = ((wv * 4 + ks) * 64 + lane) * 8;
        const short8 bhi8 = *(const short8*)&Whi[base];
        const short8 blo8 = *(const short8*)&Wlo[base];
        #pragma unroll
        for (int m = 0; m < 4; ++m) {
            acc[m] = __builtin_amdgcn_mfma_f32_16x16x32_bf16(alo[m], bhi8, acc[m], 0, 0, 0);
            acc[m] = __builtin_amdgcn_mfma_f32_16x16x32_bf16(ahi[m], blo8, acc[m], 0, 0, 0);
            acc[m] = __builtin_amdgcn_mfma_f32_16x16x32_bf16(ahi[m], bhi8, acc[m], 0, 0, 0);
        }
    }
}

// ---------------- gemm_in body (8-wave), parameterized by block id ----------------
__device__ __forceinline__ void gemm_in_body(
    unsigned int* uT, int bid,
    const float* __restrict__ A1,
    const unsigned short* __restrict__ Whi, const unsigned short* __restrict__ Wlo,
    const float* __restrict__ bias,
    unsigned short* __restrict__ out_hi, unsigned short* __restrict__ out_lo, int N)
{
    const int t    = threadIdx.x;
    const int wv   = t >> 6;
    const int lane = t & 63;
    const int lr   = lane & 15;
    const int q    = lane >> 4;
    const int rE   = wv * 8 + (lane >> 3);   // row in tile (16 elems/thread)
    const int cE   = (lane & 7) * 16;        // col base
    const int rowE = bid * 64 + rE;

    // phase 1: pack split-bf16(x) into uT
    {
        float v[16];
        if (rowE < N) {
            const int off = rowE * D + cE;
            #pragma unroll
            for (int k = 0; k < 4; ++k) {
                const float4 x = ld4(&A1[off + k * 4]);
                v[k * 4 + 0] = x.x; v[k * 4 + 1] = x.y; v[k * 4 + 2] = x.z; v[k * 4 + 3] = x.w;
            }
        } else {
            #pragma unroll
            for (int j = 0; j < 16; ++j) v[j] = 0.f;
        }
        #pragma unroll
        for (int k = 0; k < 4; ++k) {
            unsigned int pk[4];
            #pragma unroll
            for (int j = 0; j < 4; ++j) {
                const float f = v[k * 4 + j];
                const unsigned int hi = f2bf(f);
                pk[j] = (hi << 16) | f2bf(f - bf2f((unsigned short)hi));
            }
            *(uint4*)&uT[swz(rE, cE + k * 4)] = make_uint4(pk[0], pk[1], pk[2], pk[3]);
        }
    }
    __syncthreads();

    f32x4 acc[4];
    #pragma unroll
    for (int m = 0; m < 4; ++m) acc[m] = (f32x4){0.f, 0.f, 0.f, 0.f};
    coop_gemm8(uT, Whi, Wlo, wv, lane, lr, q, acc);
    __syncthreads();   // all A-reads done before C overwrite

    {
        const float b = bias[wv * 16 + lr];
        #pragma unroll
        for (int m = 0; m < 4; ++m)
            #pragma unroll
            for (int r = 0; r < 4; ++r)
                uT[swz(m * 16 + q * 4 + r, wv * 16 + lr)] = __float_as_uint(acc[m][r] + b);
    }
    __syncthreads();

    if (rowE < N) {
        const int off = rowE * D + cE;
        unsigned int w[16];
        #pragma unroll
        for (int k = 0; k < 4; ++k) {
            const uint4 a = *(const uint4*)&uT[swz(rE, cE + k * 4)];
            w[k * 4 + 0] = a.x; w[k * 4 + 1] = a.y; w[k * 4 + 2] = a.z; w[k * 4 + 3] = a.w;
        }
        #pragma unroll
        for (int h8 = 0; h8 < 2; ++h8) {
            ushort8 oh, ol;
            #pragma unroll
            for (int j = 0; j < 8; ++j) {
                const float o = __uint_as_float(w[h8 * 8 + j]);
                const unsigned short h = f2bf(o);
                oh[j] = h;
                ol[j] = f2bf(o - bf2f(h));
            }
            *(ushort8*)&out_hi[off + h8 * 8] = oh;
            *(ushort8*)&out_lo[off + h8 * 8] = ol;
        }
    }
}

// ---------------- fused setup: 5x W prepack + emb prepack + binTotal zero ----------------
__global__ __launch_bounds__(256) void setup_all(
    const float* __restrict__ W0, const float* __restrict__ W1,
    const float* __restrict__ W2, const float* __restrict__ W3,
    const float* __restrict__ W4, unsigned short* __restrict__ wp,
    const float* __restrict__ emb, unsigned int* __restrict__ embp,
    int* __restrict__ binTotal)
{
    const int T = blockIdx.x * 256 + threadIdx.x;
    if (T < 5 * D * D) {
        const int w = T / (D * D);
        const int t = T % (D * D);
        const float* W = (w == 0) ? W0 : (w == 1) ? W1 : (w == 2) ? W2 : (w == 3) ? W3 : W4;
        const int j  = t & 7;
        const int L  = (t >> 3) & 63;
        const int ks = (t >> 9) & 3;
        const int nt = t >> 11;
        const float v = W[(ks * 32 + (L >> 4) * 8 + j) * D + nt * 16 + (L & 15)];
        const unsigned short h = f2bf(v);
        unsigned short* hi = wp + (size_t)w * 2 * D * D;
        hi[t] = h;
        hi[D * D + t] = f2bf(v - bf2f(h));
    } else if (T < 5 * D * D + 6400) {
        const int i = T - 5 * D * D;
        embp[i] = (unsigned int)f2bf(emb[i * 2]) | ((unsigned int)f2bf(emb[i * 2 + 1]) << 16);
    } else if (T < 5 * D * D + 6400 + BCSTRIDE) {
        binTotal[T - 5 * D * D - 6400] = 0;
    }
}

// ---------------- K1: bin_count || gemm_in slice A (512 thr) ----------------
__global__ __launch_bounds__(512, 8) void fuse_count_gemm(
    const int* __restrict__ dst, int* __restrict__ blkcnt,
    int* __restrict__ binTotal, int E, int nbins, int csrB,
    const float* __restrict__ A1,
    const unsigned short* __restrict__ Whi, const unsigned short* __restrict__ Wlo,
    const float* __restrict__ bias,
    unsigned short* __restrict__ out_hi, unsigned short* __restrict__ out_lo,
    int N, int gemmBase)
{
    __shared__ __align__(16) unsigned int uT[64 * 128];   // 32 KB; CSR path aliases
    if ((int)blockIdx.x < csrB) {
        int* hist = (int*)uT;   // nbins ints
        const int t = threadIdx.x;
        const int i = blockIdx.x;
        for (int k = t; k < nbins; k += 512) hist[k] = 0;
        __syncthreads();
        const int e0 = i * CHUNK;
        const int e1 = min(E, e0 + CHUNK);
        for (int e = e0 + t; e < e1; e += 512) atomicAdd(&hist[dst[e] >> 8], 1);
        __syncthreads();
        for (int k = t; k < nbins; k += 512) {
            const int c = hist[k];
            blkcnt[i * BCSTRIDE + k] = c;
            if (c) atomicAdd(&binTotal[k], c);
        }
    } else {
        gemm_in_body(uT, blockIdx.x - csrB + gemmBase, A1, Whi, Wlo, bias, out_hi, out_lo, N);
    }
}

__global__ __launch_bounds__(512) void bin_scan(
    const int* __restrict__ binTotal, int* __restrict__ binStart,
    int* __restrict__ binCursor, int nbins)
{
    __shared__ int s[512];
    const int t = threadIdx.x;
    const int v = (t < nbins) ? binTotal[t] : 0;
    s[t] = v;
    __syncthreads();
    for (int off = 1; off < 512; off <<= 1) {
        const int x = (t >= off) ? s[t - off] : 0;
        __syncthreads();
        s[t] += x;
        __syncthreads();
    }
    if (t < nbins) { binStart[t] = s[t] - v; binCursor[t] = s[t] - v; }
    if (t == 0)    binStart[nbins] = s[511];
}

// ---------------- K2: bin_scatter || gemm_in slice B (512 thr) ----------------
__global__ __launch_bounds__(512, 8) void fuse_scatter_gemm(
    const int* __restrict__ src, const int* __restrict__ dst,
    const int* __restrict__ attr, const int* __restrict__ blkcnt,
    int* __restrict__ binCursor, int2* __restrict__ binned, int E, int nbins, int csrB,
    const float* __restrict__ A1,
    const unsigned short* __restrict__ Whi, const unsigned short* __restrict__ Wlo,
    const float* __restrict__ bias,
    unsigned short* __restrict__ out_hi, unsigned short* __restrict__ out_lo,
    int N, int gemmBase)
{
    __shared__ __align__(16) unsigned int uT[64 * 128];
    if ((int)blockIdx.x < csrB) {
        int* cur = (int*)uT;   // nbins ints
        const int t = threadIdx.x;
        const int i = blockIdx.x;
        for (int k = t; k < nbins; k += 512) {
            const int c = blkcnt[i * BCSTRIDE + k];
            if (c) cur[k] = atomicAdd(&binCursor[k], c);
        }
        __syncthreads();
        const int e0 = i * CHUNK;
        const int e1 = min(E, e0 + CHUNK);
        for (int e = e0 + t; e < e1; e += 512) {
            const int d = dst[e];
            const int p = atomicAdd(&cur[d >> 8], 1);
            binned[p] = make_int2(src[e] | (attr[e] << 20), d);
        }
    } else {
        gemm_in_body(uT, blockIdx.x - csrB + gemmBase, A1, Whi, Wlo, bias, out_hi, out_lo, N);
    }
}

// ---------------- K3: bin_build || gemm_in slice C (512 thr) ----------------
__global__ __launch_bounds__(512, 8) void fuse_build_gemm(
    const int2* __restrict__ binned, const int* __restrict__ binStart,
    int* __restrict__ rowptr, int* __restrict__ epack, int csrB,
    const float* __restrict__ A1,
    const unsigned short* __restrict__ Whi, const unsigned short* __restrict__ Wlo,
    const float* __restrict__ bias,
    unsigned short* __restrict__ out_hi, unsigned short* __restrict__ out_lo,
    int N, int gemmBase)
{
    __shared__ __align__(16) unsigned int uT[64 * 128];
    if ((int)blockIdx.x < csrB) {
        int* hist = (int*)uT;          // 256
        int* scn  = (int*)uT + 256;    // 256
        int* curn = (int*)uT + 512;    // 256
        const int t = threadIdx.x;
        const int b = blockIdx.x;
        if (t < 256) hist[t] = 0;
        __syncthreads();
        const int ebeg = binStart[b];
        const int eend = binStart[b + 1];
        for (int e = ebeg + t; e < eend; e += 512) atomicAdd(&hist[binned[e].y & 255], 1);
        __syncthreads();
        if (t < 256) scn[t] = hist[t];
        __syncthreads();
        for (int off = 1; off < 256; off <<= 1) {
            int x = 0;
            if (t < 256 && t >= off) x = scn[t - off];
            __syncthreads();
            if (t < 256) scn[t] += x;
            __syncthreads();
        }
        if (t < 256) {
            const int node = b * 256 + t;
            if (node < N) rowptr[node] = ebeg + scn[t];
            curn[t] = ebeg + scn[t] - hist[t];
        }
        __syncthreads();
        for (int e = ebeg + t; e < eend; e += 512) {
            const int2 v = binned[e];
            const int p = atomicAdd(&curn[v.y & 255], 1);
            epack[p] = v.x;
        }
    } else {
        gemm_in_body(uT, blockIdx.x - csrB + gemmBase, A1, Whi, Wlo, bias, out_hi, out_lo, N);
    }
}

// ---------------- fully fused GINE layer: gather + MLP (+ optional out-proj) ----------------
// Each wave gathers its own 8 node rows (R8-validated per-edge loop; emb table
// from global, L1/L2-hot) and stages fp32 results in uT via conflict-free swz
// float2 writes (rows wave-private -> no barrier before phase B, which reads and
// repacks the SAME swz addresses in place). From the first barrier on, identical
// to the R8-validated mlp_fused. No in-place hazard: input h buffer != output.
template<bool LAST>
__global__ __launch_bounds__(512, 8) void gine_fused(
    const unsigned short* __restrict__ h_hi, const unsigned short* __restrict__ h_lo,
    const int* __restrict__ rowptr, const int* __restrict__ epack,
    const unsigned int* __restrict__ embp,
    const unsigned short* __restrict__ W1hi, const unsigned short* __restrict__ W1lo,
    const float* __restrict__ b1,
    const unsigned short* __restrict__ W2hi, const unsigned short* __restrict__ W2lo,
    const float* __restrict__ b2,
    unsigned short* __restrict__ out_hi, unsigned short* __restrict__ out_lo,
    const float* __restrict__ Wout, const float* __restrict__ bout,
    float* __restrict__ outv, int N)
{
    __shared__ __align__(16) unsigned int uT[64 * 128];   // 32 KB (fp32 agg staging, then tiles)
    const int t    = threadIdx.x;
    const int wv   = t >> 6;
    const int lane = t & 63;
    const int lr   = lane & 15;
    const int q    = lane >> 4;
    const int rE   = wv * 8 + (lane >> 3);
    const int cE   = (lane & 7) * 16;
    const int rowE = blockIdx.x * 64 + rE;

    const unsigned int* hu = (const unsigned int*)h_hi;

    // ---- phase A: wave gathers its 8 node rows into uT (fp32, swz'd float2) ----
    for (int i = 0; i < 8; ++i) {
        const int row  = wv * 8 + i;
        const int node = blockIdx.x * 64 + row;
        if (node >= N) break;   // wave-uniform
        int start = (node == 0) ? 0 : rowptr[node - 1];
        int end   = rowptr[node];
        start = __builtin_amdgcn_readfirstlane(start);
        end   = __builtin_amdgcn_readfirstlane(end);

        float ax = 0.f, ay = 0.f;
        int j = start;

        for (; j < end && (j & 3); ++j) {
            const int p0 = __builtin_amdgcn_readfirstlane(epack[j]);
            const unsigned int u0 = hu[(p0 & 0xFFFFF) * 64 + lane];
            const unsigned int v0 = embp[(p0 >> 20) * 64 + lane];
            ax += fmaxf(blo(u0) + blo(v0), 0.f);
            ay += fmaxf(bhi(u0) + bhi(v0), 0.f);
        }

        for (; j + 7 < end; j += 8) {
            const int4 pk0 = *(const int4*)&epack[j];
            const int4 pk1 = *(const int4*)&epack[j + 4];
            int p[8];
            p[0] = __builtin_amdgcn_readfirstlane(pk0.x);
            p[1] = __builtin_amdgcn_readfirstlane(pk0.y);
            p[2] = __builtin_amdgcn_readfirstlane(pk0.z);
            p[3] = __builtin_amdgcn_readfirstlane(pk0.w);
            p[4] = __builtin_amdgcn_readfirstlane(pk1.x);
            p[5] = __builtin_amdgcn_readfirstlane(pk1.y);
            p[6] = __builtin_amdgcn_readfirstlane(pk1.z);
            p[7] = __builtin_amdgcn_readfirstlane(pk1.w);
            unsigned int u[8], v[8];
            #pragma unroll
            for (int k = 0; k < 8; ++k) u[k] = hu[(p[k] & 0xFFFFF) * 64 + lane];
            #pragma unroll
            for (int k = 0; k < 8; ++k) v[k] = embp[(p[k] >> 20) * 64 + lane];
            #pragma unroll
            for (int k = 0; k < 8; ++k) {
                ax += fmaxf(blo(u[k]) + blo(v[k]), 0.f);
                ay += fmaxf(bhi(u[k]) + bhi(v[k]), 0.f);
            }
        }

        if (j + 3 < end) {
            const int4 pk0 = *(const int4*)&epack[j];
            int p[4];
            p[0] = __builtin_amdgcn_readfirstlane(pk0.x);
            p[1] = __builtin_amdgcn_readfirstlane(pk0.y);
            p[2] = __builtin_amdgcn_readfirstlane(pk0.z);
            p[3] = __builtin_amdgcn_readfirstlane(pk0.w);
            unsigned int u[4], v[4];
            #pragma unroll
            for (int k = 0; k < 4; ++k) u[k] = hu[(p[k] & 0xFFFFF) * 64 + lane];
            #pragma unroll
            for (int k = 0; k < 4; ++k) v[k] = embp[(p[k] >> 20) * 64 + lane];
            #pragma unroll
            for (int k = 0; k < 4; ++k) {
                ax += fmaxf(blo(u[k]) + blo(v[k]), 0.f);
                ay += fmaxf(bhi(u[k]) + bhi(v[k]), 0.f);
            }
            j += 4;
        }

        for (; j < end; ++j) {
            const int p0 = __builtin_amdgcn_readfirstlane(epack[j]);
            const unsigned int u0 = hu[(p0 & 0xFFFFF) * 64 + lane];
            const unsigned int v0 = embp[(p0 >> 20) * 64 + lane];
            ax += fmaxf(blo(u0) + blo(v0), 0.f);
            ay += fmaxf(bhi(u0) + bhi(v0), 0.f);
        }

        // stage fp32 pair for dims (2*lane, 2*lane+1): unit (lane>>1)^(row&7),
        // 32 units x 2 lanes -> conflict-free ds_write_b64
        *(float2*)&uT[swz(row, 2 * lane)] = make_float2(ax, ay);
    }
    // no barrier: uT rows [wv*8, wv*8+8) written and read by this wave only

    // ---- phase B: read agg fp32 from uT, add residual h, repack split-bf16 in place ----
    {
        float v[16];
        if (rowE < N) {
            #pragma unroll
            for (int k = 0; k < 4; ++k) {
                const uint4 a = *(const uint4*)&uT[swz(rE, cE + k * 4)];
                v[k * 4 + 0] = __uint_as_float(a.x);
                v[k * 4 + 1] = __uint_as_float(a.y);
                v[k * 4 + 2] = __uint_as_float(a.z);
                v[k * 4 + 3] = __uint_as_float(a.w);
            }
            const int off = rowE * D + cE;
            #pragma unroll
            for (int h8 = 0; h8 < 2; ++h8) {
                const ushort8 hh = *(const ushort8*)&h_hi[off + h8 * 8];
                const ushort8 ll = *(const ushort8*)&h_lo[off + h8 * 8];
                #pragma unroll
                for (int j = 0; j < 8; ++j) v[h8 * 8 + j] += bf2f(hh[j]) + bf2f(ll[j]);
            }
        } else {
            #pragma unroll
            for (int j = 0; j < 16; ++j) v[j] = 0.f;
        }
        #pragma unroll
        for (int k = 0; k < 4; ++k) {
            unsigned int pk[4];
            #pragma unroll
            for (int j = 0; j < 4; ++j) {
                const float f = v[k * 4 + j];
                const unsigned int hi = f2bf(f);
                pk[j] = (hi << 16) | f2bf(f - bf2f((unsigned short)hi));
            }
            *(uint4*)&uT[swz(rE, cE + k * 4)] = make_uint4(pk[0], pk[1], pk[2], pk[3]);
        }
    }
    __syncthreads();

    // GEMM1
    f32x4 acc[4];
    #pragma unroll
    for (int m = 0; m < 4; ++m) acc[m] = (f32x4){0.f, 0.f, 0.f, 0.f};
    coop_gemm8(uT, W1hi, W1lo, wv, lane, lr, q, acc);
    __syncthreads();   // A-reads done before mid overwrite

    // mid = relu(acc + b1) -> packed split-bf16 in uT
    {
        const float b = b1[wv * 16 + lr];
        #pragma unroll
        for (int m = 0; m < 4; ++m)
            #pragma unroll
            for (int r = 0; r < 4; ++r) {
                const float o = fmaxf(acc[m][r] + b, 0.f);
                const unsigned int hi = f2bf(o);
                const unsigned int lo = f2bf(o - bf2f((unsigned short)hi));
                uT[swz(m * 16 + q * 4 + r, wv * 16 + lr)] = (hi << 16) | lo;
            }
    }
    __syncthreads();

    // GEMM2
    f32x4 acc2[4];
    #pragma unroll
    for (int m = 0; m < 4; ++m) acc2[m] = (f32x4){0.f, 0.f, 0.f, 0.f};
    coop_gemm8(uT, W2hi, W2lo, wv, lane, lr, q, acc2);
    __syncthreads();   // mid-reads done before C2 overwrite

    {
        const float b = b2[wv * 16 + lr];
        #pragma unroll
        for (int m = 0; m < 4; ++m)
            #pragma unroll
            for (int r = 0; r < 4; ++r)
                uT[swz(m * 16 + q * 4 + r, wv * 16 + lr)] = __float_as_uint(acc2[m][r] + b);
    }
    __syncthreads();

    // epilogue: 16 elems per thread on row rE
    if (LAST) {
        float accv = 0.f;
        if (rowE < N) {
            const int off = rowE * D + cE;
            unsigned int w[16];
            #pragma unroll
            for (int k = 0; k < 4; ++k) {
                const uint4 a = *(const uint4*)&uT[swz(rE, cE + k * 4)];
                w[k * 4 + 0] = a.x; w[k * 4 + 1] = a.y; w[k * 4 + 2] = a.z; w[k * 4 + 3] = a.w;
            }
            #pragma unroll
            for (int h8 = 0; h8 < 2; ++h8) {
                const ushort8 hh = *(const ushort8*)&h_hi[off + h8 * 8];
                const ushort8 ll = *(const ushort8*)&h_lo[off + h8 * 8];
                const float4 w0 = ld4(&Wout[cE + h8 * 8]);
                const float4 w1 = ld4(&Wout[cE + h8 * 8 + 4]);
                float o[8];
                #pragma unroll
                for (int j = 0; j < 8; ++j)
                    o[j] = fmaxf(__uint_as_float(w[h8 * 8 + j]) + bf2f(hh[j]) + bf2f(ll[j]), 0.f);
                accv += o[0] * w0.x + o[1] * w0.y + o[2] * w0.z + o[3] * w0.w;
                accv += o[4] * w1.x + o[5] * w1.y + o[6] * w1.z + o[7] * w1.w;
            }
        }
        accv += __shfl_xor(accv, 1);
        accv += __shfl_xor(accv, 2);
        accv += __shfl_xor(accv, 4);
        if ((lane & 7) == 0 && rowE < N) outv[rowE] = accv + bout[0];
    } else if (rowE < N) {
        const int off = rowE * D + cE;
        unsigned int w[16];
        #pragma unroll
        for (int k = 0; k < 4; ++k) {
            const uint4 a = *(const uint4*)&uT[swz(rE, cE + k * 4)];
            w[k * 4 + 0] = a.x; w[k * 4 + 1] = a.y; w[k * 4 + 2] = a.z; w[k * 4 + 3] = a.w;
        }
        #pragma unroll
        for (int h8 = 0; h8 < 2; ++h8) {
            const ushort8 hh = *(const ushort8*)&h_hi[off + h8 * 8];
            const ushort8 ll = *(const ushort8*)&h_lo[off + h8 * 8];
            ushort8 oh, ol;
            #pragma unroll
            for (int j = 0; j < 8; ++j) {
                const float o = fmaxf(__uint_as_float(w[h8 * 8 + j]) + bf2f(hh[j]) + bf2f(ll[j]), 0.f);
                const unsigned short h = f2bf(o);
                oh[j] = h;
                ol[j] = f2bf(o - bf2f(h));
            }
            *(ushort8*)&out_hi[off + h8 * 8] = oh;
            *(ushort8*)&out_lo[off + h8 * 8] = ol;
        }
    }
}

extern "C" void kernel_launch(void* const* d_in, const int* in_sizes, int n_in,
                              void* d_out, int out_size, void* d_ws, size_t ws_size,
                              hipStream_t stream)
{
    const float* x     = (const float*)d_in[0];
    const int*   ei    = (const int*)  d_in[1];
    const int*   attr  = (const int*)  d_in[2];
    const float* emb   = (const float*)d_in[3];
    const float* Win   = (const float*)d_in[4];
    const float* b_in  = (const float*)d_in[5];
    const float* W1_0  = (const float*)d_in[6];
    const float* b1_0  = (const float*)d_in[7];
    const float* W2_0  = (const float*)d_in[8];
    const float* b2_0  = (const float*)d_in[9];
    const float* W1_1  = (const float*)d_in[10];
    const float* b1_1  = (const float*)d_in[11];
    const float* W2_1  = (const float*)d_in[12];
    const float* b2_1  = (const float*)d_in[13];
    const float* Wout  = (const float*)d_in[14];
    const float* b_out = (const float*)d_in[15];
    float* out = (float*)d_out;

    const int N = NN;
    const int E = in_sizes[2];
    const int* srcp = ei;
    const int* dstp = ei + E;
    const int nbins = (N + 255) >> 8;
    const int eblocks = (E + CHUNK - 1) / CHUNK;

    // persistent workspace
    unsigned short* h_hi = (unsigned short*)d_ws;        // N*D ushort   (buffer A hi)
    unsigned short* h_lo = h_hi + (size_t)N * D;         // N*D ushort   (buffer A lo)
    float* aggspace = (float*)(h_lo + (size_t)N * D);    // N*D float: CSR scratch, then buffer B
    int*   rowptr = (int*)(aggspace + (size_t)N * D);    // N
    int*   epack  = rowptr + N;                          // E
    unsigned short* wp = (unsigned short*)(epack + E);   // 5*2*D*D
    unsigned short* Whi[5], *Wlo[5];
    for (int i = 0; i < 5; ++i) {
        Whi[i] = wp + (size_t)i * 2 * D * D;
        Wlo[i] = Whi[i] + D * D;
    }
    unsigned int* embp = (unsigned int*)(wp + 5 * 2 * D * D);  // 100*64 uint
    // CSR-build scratch aliased into aggspace (dead before gine_fused<false> writes)
    int2* binned    = (int2*)aggspace;                    // E
    int*  blkcnt    = (int*)(binned + E);                 // eblocks*BCSTRIDE
    int*  binTotal  = blkcnt + eblocks * BCSTRIDE;        // nbins
    int*  binStart  = binTotal + BCSTRIDE;                // nbins+1
    int*  binCursor = binStart + BCSTRIDE;                // nbins
    // double-buffered h: buffer B in aggspace (N*D*4 B == 2 * N*D*2 B)
    unsigned short* hB_hi = (unsigned short*)aggspace;    // N*D ushort
    unsigned short* hB_lo = hB_hi + (size_t)N * D;        // N*D ushort

    const int fgrid = (N + 63) / 64;                      // 1563 tiles
    const int sgrid = (5 * D * D + 6400 + BCSTRIDE + 255) / 256;

    // gemm_in tile slices overlapped with CSR stages
    const int G1 = 200;
    const int G2 = 700;
    const int G3 = fgrid - G1 - G2;                       // 663

    // ---- fused setup: W/emb prepack + binTotal zero ----
    setup_all<<<sgrid, dim3(256), 0, stream>>>(Win, W1_0, W2_0, W1_1, W2_1, wp, emb, embp, binTotal);

    // ---- CSR build overlapped with gemm_in slices (512-thr blocks) ----
    fuse_count_gemm<<<eblocks + G1, dim3(512), 0, stream>>>(
        dstp, blkcnt, binTotal, E, nbins, eblocks,
        x, Whi[0], Wlo[0], b_in, h_hi, h_lo, N, 0);
    bin_scan<<<1, 512, 0, stream>>>(binTotal, binStart, binCursor, nbins);
    fuse_scatter_gemm<<<eblocks + G2, dim3(512), 0, stream>>>(
        srcp, dstp, attr, blkcnt, binCursor, binned, E, nbins, eblocks,
        x, Whi[0], Wlo[0], b_in, h_hi, h_lo, N, G1);
    fuse_build_gemm<<<nbins + G3, dim3(512), 0, stream>>>(
        binned, binStart, rowptr, epack, nbins,
        x, Whi[0], Wlo[0], b_in, h_hi, h_lo, N, G1 + G2);

    // ---- layer 0: gather+MLP fused, h(A) -> hB ----
    gine_fused<false><<<fgrid, dim3(512), 0, stream>>>(
        h_hi, h_lo, rowptr, epack, embp,
        Whi[1], Wlo[1], b1_0, Whi[2], Wlo[2], b2_0,
        hB_hi, hB_lo, nullptr, nullptr, nullptr, N);

    // ---- layer 1 + fused output projection: hB -> out ----
    gine_fused<true><<<fgrid, dim3(512), 0, stream>>>(
        hB_hi, hB_lo, rowptr, epack, embp,
        Whi[3], Wlo[3], b1_1, Whi[4], Wlo[4], b2_1,
        nullptr, nullptr, Wout, b_out, out, N);
}

// Round 11
// 383.236 us; speedup vs baseline: 1.0980x; 1.0368x over previous
//
#include <hip/hip_runtime.h>

#define NN 100000
#define D 128
#define CHUNK 4096
#define BCSTRIDE 392

typedef __attribute__((ext_vector_type(8))) short short8;
typedef __attribute__((ext_vector_type(8))) unsigned short ushort8;
typedef __attribute__((ext_vector_type(4))) float f32x4;

__device__ __forceinline__ float4 ld4(const float* p) { return *(const float4*)p; }

__device__ __forceinline__ unsigned short f2bf(float f) {
    unsigned int u = __float_as_uint(f);
    unsigned int r = u + 0x7fffu + ((u >> 16) & 1u);   // RNE
    return (unsigned short)(r >> 16);
}
__device__ __forceinline__ float bf2f(unsigned short h) {
    return __uint_as_float(((unsigned int)h) << 16);
}
__device__ __forceinline__ float blo(unsigned int u) { return __uint_as_float(u << 16); }
__device__ __forceinline__ float bhi(unsigned int u) { return __uint_as_float(u & 0xffff0000u); }

// fp32 staging layout (R6-validated): 64 rows x 128 uints, 16B-unit XOR'd with row&7.
__device__ __forceinline__ int swz(int r, int c) {
    return r * 128 + ((((c >> 2) ^ (r & 7)) << 2) | (c & 3));
}
// split-bf16 planes (R11): plane p in {0=hi,1=lo}, 64 rows x 128 bf16 each (16 KB/plane).
// 16B-unit index XOR'd with row&7 -> same conflict floor as the packed layout, but
// ds_read_b128 delivers 8 bf16 DIRECTLY in MFMA operand layout (zero unpack VALU).
__device__ __forceinline__ int pidx(int p, int r, int c) {
    return p * 8192 + r * 128 + (((c >> 3) ^ (r & 7)) << 3) + (c & 7);
}

// 8-wave block-cooperative GEMM (R8 structure, R11 split-plane reads): wave wv
// computes output cols [wv*16, wv*16+16) for all 64 rows; 32 waves/CU.
__device__ __forceinline__ void coop_gemm8(
    const unsigned short* Hs,
    const unsigned short* __restrict__ Whi, const unsigned short* __restrict__ Wlo,
    int wv, int lane, int lr, int q, f32x4 acc[4])
{
    #pragma unroll
    for (int ks = 0; ks < 4; ++ks) {
        short8 ahi[4], alo[4];
        #pragma unroll
        for (int m = 0; m < 4; ++m) {
            const int row = m * 16 + lr;
            const int c   = ks * 32 + q * 8;
            ahi[m] = *(const short8*)&Hs[pidx(0, row, c)];
            alo[m] = *(const short8*)&Hs[pidx(1, row, c)];
        }
        const int base = ((wv * 4 + ks) * 64 + lane) * 8;
        const short8 bhi8 = *(const short8*)&Whi[base];
        const short8 blo8 = *(const short8*)&Wlo[base];
        #pragma unroll
        for (int m = 0; m < 4; ++m) {
            acc[m] = __builtin_amdgcn_mfma_f32_16x16x32_bf16(alo[m], bhi8, acc[m], 0, 0, 0);
            acc[m] = __builtin_amdgcn_mfma_f32_16x16x32_bf16(ahi[m], blo8, acc[m], 0, 0, 0);
            acc[m] = __builtin_amdgcn_mfma_f32_16x16x32_bf16(ahi[m], bhi8, acc[m], 0, 0, 0);
        }
    }
}

// ---------------- gemm_in body (8-wave, split planes), parameterized by block id ----------------
__device__ __forceinline__ void gemm_in_body(
    unsigned short* Hs, int bid,
    const float* __restrict__ A1,
    const unsigned short* __restrict__ Whi, const unsigned short* __restrict__ Wlo,
    const float* __restrict__ bias,
    unsigned short* __restrict__ out_hi, unsigned short* __restrict__ out_lo, int N)
{
    const int t    = threadIdx.x;
    const int wv   = t >> 6;
    const int lane = t & 63;
    const int lr   = lane & 15;
    const int q    = lane >> 4;
    const int rE   = wv * 8 + (lane >> 3);   // row in tile (16 elems/thread)
    const int cE   = (lane & 7) * 16;        // col base
    const int rowE = bid * 64 + rE;

    // phase 1: split-bf16(x) straight into the hi/lo planes
    {
        float v[16];
        if (rowE < N) {
            const int off = rowE * D + cE;
            #pragma unroll
            for (int k = 0; k < 4; ++k) {
                const float4 x = ld4(&A1[off + k * 4]);
                v[k * 4 + 0] = x.x; v[k * 4 + 1] = x.y; v[k * 4 + 2] = x.z; v[k * 4 + 3] = x.w;
            }
        } else {
            #pragma unroll
            for (int j = 0; j < 16; ++j) v[j] = 0.f;
        }
        #pragma unroll
        for (int h8 = 0; h8 < 2; ++h8) {
            ushort8 hv, lv;
            #pragma unroll
            for (int j = 0; j < 8; ++j) {
                const float f = v[h8 * 8 + j];
                const unsigned short hi = f2bf(f);
                hv[j] = hi;
                lv[j] = f2bf(f - bf2f(hi));
            }
            *(ushort8*)&Hs[pidx(0, rE, cE + h8 * 8)] = hv;
            *(ushort8*)&Hs[pidx(1, rE, cE + h8 * 8)] = lv;
        }
    }
    __syncthreads();

    f32x4 acc[4];
    #pragma unroll
    for (int m = 0; m < 4; ++m) acc[m] = (f32x4){0.f, 0.f, 0.f, 0.f};
    coop_gemm8(Hs, Whi, Wlo, wv, lane, lr, q, acc);
    __syncthreads();   // all A-reads done before C overwrite

    unsigned int* uT = (unsigned int*)Hs;   // fp32 staging view
    {
        const float b = bias[wv * 16 + lr];
        #pragma unroll
        for (int m = 0; m < 4; ++m)
            #pragma unroll
            for (int r = 0; r < 4; ++r)
                uT[swz(m * 16 + q * 4 + r, wv * 16 + lr)] = __float_as_uint(acc[m][r] + b);
    }
    __syncthreads();

    if (rowE < N) {
        const int off = rowE * D + cE;
        unsigned int w[16];
        #pragma unroll
        for (int k = 0; k < 4; ++k) {
            const uint4 a = *(const uint4*)&uT[swz(rE, cE + k * 4)];
            w[k * 4 + 0] = a.x; w[k * 4 + 1] = a.y; w[k * 4 + 2] = a.z; w[k * 4 + 3] = a.w;
        }
        #pragma unroll
        for (int h8 = 0; h8 < 2; ++h8) {
            ushort8 oh, ol;
            #pragma unroll
            for (int j = 0; j < 8; ++j) {
                const float o = __uint_as_float(w[h8 * 8 + j]);
                const unsigned short h = f2bf(o);
                oh[j] = h;
                ol[j] = f2bf(o - bf2f(h));
            }
            *(ushort8*)&out_hi[off + h8 * 8] = oh;
            *(ushort8*)&out_lo[off + h8 * 8] = ol;
        }
    }
}

// ---------------- fused setup: 5x W prepack + emb prepack + binTotal zero ----------------
__global__ __launch_bounds__(256) void setup_all(
    const float* __restrict__ W0, const float* __restrict__ W1,
    const float* __restrict__ W2, const float* __restrict__ W3,
    const float* __restrict__ W4, unsigned short* __restrict__ wp,
    const float* __restrict__ emb, unsigned int* __restrict__ embp,
    int* __restrict__ binTotal)
{
    const int T = blockIdx.x * 256 + threadIdx.x;
    if (T < 5 * D * D) {
        const int w = T / (D * D);
        const int t = T % (D * D);
        const float* W = (w == 0) ? W0 : (w == 1) ? W1 : (w == 2) ? W2 : (w == 3) ? W3 : W4;
        const int j  = t & 7;
        const int L  = (t >> 3) & 63;
        const int ks = (t >> 9) & 3;
        const int nt = t >> 11;
        const float v = W[(ks * 32 + (L >> 4) * 8 + j) * D + nt * 16 + (L & 15)];
        const unsigned short h = f2bf(v);
        unsigned short* hi = wp + (size_t)w * 2 * D * D;
        hi[t] = h;
        hi[D * D + t] = f2bf(v - bf2f(h));
    } else if (T < 5 * D * D + 6400) {
        const int i = T - 5 * D * D;
        embp[i] = (unsigned int)f2bf(emb[i * 2]) | ((unsigned int)f2bf(emb[i * 2 + 1]) << 16);
    } else if (T < 5 * D * D + 6400 + BCSTRIDE) {
        binTotal[T - 5 * D * D - 6400] = 0;
    }
}

// ---------------- K1: bin_count || gemm_in slice A (512 thr) ----------------
__global__ __launch_bounds__(512, 8) void fuse_count_gemm(
    const int* __restrict__ dst, int* __restrict__ blkcnt,
    int* __restrict__ binTotal, int E, int nbins, int csrB,
    const float* __restrict__ A1,
    const unsigned short* __restrict__ Whi, const unsigned short* __restrict__ Wlo,
    const float* __restrict__ bias,
    unsigned short* __restrict__ out_hi, unsigned short* __restrict__ out_lo,
    int N, int gemmBase)
{
    __shared__ __align__(16) unsigned short Hs[2 * 64 * 128];   // 32 KB; CSR path aliases
    if ((int)blockIdx.x < csrB) {
        int* hist = (int*)Hs;   // nbins ints
        const int t = threadIdx.x;
        const int i = blockIdx.x;
        for (int k = t; k < nbins; k += 512) hist[k] = 0;
        __syncthreads();
        const int e0 = i * CHUNK;
        const int e1 = min(E, e0 + CHUNK);
        for (int e = e0 + t; e < e1; e += 512) atomicAdd(&hist[dst[e] >> 8], 1);
        __syncthreads();
        for (int k = t; k < nbins; k += 512) {
            const int c = hist[k];
            blkcnt[i * BCSTRIDE + k] = c;
            if (c) atomicAdd(&binTotal[k], c);
        }
    } else {
        gemm_in_body(Hs, blockIdx.x - csrB + gemmBase, A1, Whi, Wlo, bias, out_hi, out_lo, N);
    }
}

__global__ __launch_bounds__(512) void bin_scan(
    const int* __restrict__ binTotal, int* __restrict__ binStart,
    int* __restrict__ binCursor, int nbins)
{
    __shared__ int s[512];
    const int t = threadIdx.x;
    const int v = (t < nbins) ? binTotal[t] : 0;
    s[t] = v;
    __syncthreads();
    for (int off = 1; off < 512; off <<= 1) {
        const int x = (t >= off) ? s[t - off] : 0;
        __syncthreads();
        s[t] += x;
        __syncthreads();
    }
    if (t < nbins) { binStart[t] = s[t] - v; binCursor[t] = s[t] - v; }
    if (t == 0)    binStart[nbins] = s[511];
}

// ---------------- K2: bin_scatter || gemm_in slice B (512 thr) ----------------
__global__ __launch_bounds__(512, 8) void fuse_scatter_gemm(
    const int* __restrict__ src, const int* __restrict__ dst,
    const int* __restrict__ attr, const int* __restrict__ blkcnt,
    int* __restrict__ binCursor, int2* __restrict__ binned, int E, int nbins, int csrB,
    const float* __restrict__ A1,
    const unsigned short* __restrict__ Whi, const unsigned short* __restrict__ Wlo,
    const float* __restrict__ bias,
    unsigned short* __restrict__ out_hi, unsigned short* __restrict__ out_lo,
    int N, int gemmBase)
{
    __shared__ __align__(16) unsigned short Hs[2 * 64 * 128];
    if ((int)blockIdx.x < csrB) {
        int* cur = (int*)Hs;   // nbins ints
        const int t = threadIdx.x;
        const int i = blockIdx.x;
        for (int k = t; k < nbins; k += 512) {
            const int c = blkcnt[i * BCSTRIDE + k];
            if (c) cur[k] = atomicAdd(&binCursor[k], c);
        }
        __syncthreads();
        const int e0 = i * CHUNK;
        const int e1 = min(E, e0 + CHUNK);
        for (int e = e0 + t; e < e1; e += 512) {
            const int d = dst[e];
            const int p = atomicAdd(&cur[d >> 8], 1);
            binned[p] = make_int2(src[e] | (attr[e] << 20), d);
        }
    } else {
        gemm_in_body(Hs, blockIdx.x - csrB + gemmBase, A1, Whi, Wlo, bias, out_hi, out_lo, N);
    }
}

// ---------------- K3: bin_build || gemm_in slice C (512 thr) ----------------
__global__ __launch_bounds__(512, 8) void fuse_build_gemm(
    const int2* __restrict__ binned, const int* __restrict__ binStart,
    int* __restrict__ rowptr, int* __restrict__ epack, int csrB,
    const float* __restrict__ A1,
    const unsigned short* __restrict__ Whi, const unsigned short* __restrict__ Wlo,
    const float* __restrict__ bias,
    unsigned short* __restrict__ out_hi, unsigned short* __restrict__ out_lo,
    int N, int gemmBase)
{
    __shared__ __align__(16) unsigned short Hs[2 * 64 * 128];
    if ((int)blockIdx.x < csrB) {
        int* hist = (int*)Hs;          // 256
        int* scn  = (int*)Hs + 256;    // 256
        int* curn = (int*)Hs + 512;    // 256
        const int t = threadIdx.x;
        const int b = blockIdx.x;
        if (t < 256) hist[t] = 0;
        __syncthreads();
        const int ebeg = binStart[b];
        const int eend = binStart[b + 1];
        for (int e = ebeg + t; e < eend; e += 512) atomicAdd(&hist[binned[e].y & 255], 1);
        __syncthreads();
        if (t < 256) scn[t] = hist[t];
        __syncthreads();
        for (int off = 1; off < 256; off <<= 1) {
            int x = 0;
            if (t < 256 && t >= off) x = scn[t - off];
            __syncthreads();
            if (t < 256) scn[t] += x;
            __syncthreads();
        }
        if (t < 256) {
            const int node = b * 256 + t;
            if (node < N) rowptr[node] = ebeg + scn[t];
            curn[t] = ebeg + scn[t] - hist[t];
        }
        __syncthreads();
        for (int e = ebeg + t; e < eend; e += 512) {
            const int2 v = binned[e];
            const int p = atomicAdd(&curn[v.y & 255], 1);
            epack[p] = v.x;
        }
    } else {
        gemm_in_body(Hs, blockIdx.x - csrB + gemmBase, A1, Whi, Wlo, bias, out_hi, out_lo, N);
    }
}

// ---------------- fully fused GINE layer: gather + MLP (+ optional out-proj) ----------------
// Phase A: each wave gathers its 8 node rows, adds the inner residual, and writes
// split-bf16 DIRECTLY to the hi/lo planes (conflict-free b32 writes) -> the old
// fp32-staging phase B is gone. GEMMs read planes with zero unpack VALU.
template<bool LAST>
__global__ __launch_bounds__(512, 8) void gine_fused(
    const unsigned short* __restrict__ h_hi, const unsigned short* __restrict__ h_lo,
    const int* __restrict__ rowptr, const int* __restrict__ epack,
    const unsigned int* __restrict__ embp,
    const unsigned short* __restrict__ W1hi, const unsigned short* __restrict__ W1lo,
    const float* __restrict__ b1,
    const unsigned short* __restrict__ W2hi, const unsigned short* __restrict__ W2lo,
    const float* __restrict__ b2,
    unsigned short* __restrict__ out_hi, unsigned short* __restrict__ out_lo,
    const float* __restrict__ Wout, const float* __restrict__ bout,
    float* __restrict__ outv, int N)
{
    __shared__ __align__(16) unsigned short Hs[2 * 64 * 128];   // 32 KB
    const int t    = threadIdx.x;
    const int wv   = t >> 6;
    const int lane = t & 63;
    const int lr   = lane & 15;
    const int q    = lane >> 4;
    const int rE   = wv * 8 + (lane >> 3);
    const int cE   = (lane & 7) * 16;
    const int rowE = blockIdx.x * 64 + rE;

    const unsigned int* hu = (const unsigned int*)h_hi;
    const unsigned int* hl = (const unsigned int*)h_lo;

    // ---- phase A: gather 8 rows; add inner residual; split-bf16 into planes ----
    for (int i = 0; i < 8; ++i) {
        const int row  = wv * 8 + i;
        const int node = blockIdx.x * 64 + row;
        if (node >= N) break;   // wave-uniform; unwritten tail rows produce garbage
                                // confined to discarded C rows (row-local MFMA dep)
        int start = (node == 0) ? 0 : rowptr[node - 1];
        int end   = rowptr[node];
        start = __builtin_amdgcn_readfirstlane(start);
        end   = __builtin_amdgcn_readfirstlane(end);

        float ax = 0.f, ay = 0.f;
        int j = start;

        for (; j < end && (j & 3); ++j) {
            const int p0 = __builtin_amdgcn_readfirstlane(epack[j]);
            const unsigned int u0 = hu[(p0 & 0xFFFFF) * 64 + lane];
            const unsigned int v0 = embp[(p0 >> 20) * 64 + lane];
            ax += fmaxf(blo(u0) + blo(v0), 0.f);
            ay += fmaxf(bhi(u0) + bhi(v0), 0.f);
        }

        for (; j + 7 < end; j += 8) {
            const int4 pk0 = *(const int4*)&epack[j];
            const int4 pk1 = *(const int4*)&epack[j + 4];
            int p[8];
            p[0] = __builtin_amdgcn_readfirstlane(pk0.x);
            p[1] = __builtin_amdgcn_readfirstlane(pk0.y);
            p[2] = __builtin_amdgcn_readfirstlane(pk0.z);
            p[3] = __builtin_amdgcn_readfirstlane(pk0.w);
            p[4] = __builtin_amdgcn_readfirstlane(pk1.x);
            p[5] = __builtin_amdgcn_readfirstlane(pk1.y);
            p[6] = __builtin_amdgcn_readfirstlane(pk1.z);
            p[7] = __builtin_amdgcn_readfirstlane(pk1.w);
            unsigned int u[8], v[8];
            #pragma unroll
            for (int k = 0; k < 8; ++k) u[k] = hu[(p[k] & 0xFFFFF) * 64 + lane];
            #pragma unroll
            for (int k = 0; k < 8; ++k) v[k] = embp[(p[k] >> 20) * 64 + lane];
            #pragma unroll
            for (int k = 0; k < 8; ++k) {
                ax += fmaxf(blo(u[k]) + blo(v[k]), 0.f);
                ay += fmaxf(bhi(u[k]) + bhi(v[k]), 0.f);
            }
        }

        if (j + 3 < end) {
            const int4 pk0 = *(const int4*)&epack[j];
            int p[4];
            p[0] = __builtin_amdgcn_readfirstlane(pk0.x);
            p[1] = __builtin_amdgcn_readfirstlane(pk0.y);
            p[2] = __builtin_amdgcn_readfirstlane(pk0.z);
            p[3] = __builtin_amdgcn_readfirstlane(pk0.w);
            unsigned int u[4], v[4];
            #pragma unroll
            for (int k = 0; k < 4; ++k) u[k] = hu[(p[k] & 0xFFFFF) * 64 + lane];
            #pragma unroll
            for (int k = 0; k < 4; ++k) v[k] = embp[(p[k] >> 20) * 64 + lane];
            #pragma unroll
            for (int k = 0; k < 4; ++k) {
                ax += fmaxf(blo(u[k]) + blo(v[k]), 0.f);
                ay += fmaxf(bhi(u[k]) + bhi(v[k]), 0.f);
            }
            j += 4;
        }

        for (; j < end; ++j) {
            const int p0 = __builtin_amdgcn_readfirstlane(epack[j]);
            const unsigned int u0 = hu[(p0 & 0xFFFFF) * 64 + lane];
            const unsigned int v0 = embp[(p0 >> 20) * 64 + lane];
            ax += fmaxf(blo(u0) + blo(v0), 0.f);
            ay += fmaxf(bhi(u0) + bhi(v0), 0.f);
        }

        // inner residual + split-bf16; dims (2*lane, 2*lane+1) -> one b32 per plane
        const unsigned int uh = hu[node * 64 + lane];
        const unsigned int ul = hl[node * 64 + lane];
        const float vx = ax + blo(uh) + blo(ul);
        const float vy = ay + bhi(uh) + bhi(ul);
        const unsigned int hx = f2bf(vx), hy = f2bf(vy);
        const unsigned int lx = f2bf(vx - bf2f((unsigned short)hx));
        const unsigned int ly = f2bf(vy - bf2f((unsigned short)hy));
        *(unsigned int*)&Hs[pidx(0, row, 2 * lane)] = hx | (hy << 16);
        *(unsigned int*)&Hs[pidx(1, row, 2 * lane)] = lx | (ly << 16);
    }
    __syncthreads();

    // GEMM1
    f32x4 acc[4];
    #pragma unroll
    for (int m = 0; m < 4; ++m) acc[m] = (f32x4){0.f, 0.f, 0.f, 0.f};
    coop_gemm8(Hs, W1hi, W1lo, wv, lane, lr, q, acc);
    __syncthreads();   // A-reads done before mid overwrite

    // mid = relu(acc + b1) -> split planes (transpose via per-element b16 writes)
    {
        const float b = b1[wv * 16 + lr];
        const int col = wv * 16 + lr;
        #pragma unroll
        for (int m = 0; m < 4; ++m)
            #pragma unroll
            for (int r = 0; r < 4; ++r) {
                const int row = m * 16 + q * 4 + r;
                const float o = fmaxf(acc[m][r] + b, 0.f);
                const unsigned short hi = f2bf(o);
                Hs[pidx(0, row, col)] = hi;
                Hs[pidx(1, row, col)] = f2bf(o - bf2f(hi));
            }
    }
    __syncthreads();

    // GEMM2
    f32x4 acc2[4];
    #pragma unroll
    for (int m = 0; m < 4; ++m) acc2[m] = (f32x4){0.f, 0.f, 0.f, 0.f};
    coop_gemm8(Hs, W2hi, W2lo, wv, lane, lr, q, acc2);
    __syncthreads();   // mid-reads done before C2 overwrite

    unsigned int* uT = (unsigned int*)Hs;   // fp32 staging view (R8-validated pattern)
    {
        const float b = b2[wv * 16 + lr];
        #pragma unroll
        for (int m = 0; m < 4; ++m)
            #pragma unroll
            for (int r = 0; r < 4; ++r)
                uT[swz(m * 16 + q * 4 + r, wv * 16 + lr)] = __float_as_uint(acc2[m][r] + b);
    }
    __syncthreads();

    // epilogue: 16 elems per thread on row rE (outer residual + relu)
    if (LAST) {
        float accv = 0.f;
        if (rowE < N) {
            const int off = rowE * D + cE;
            unsigned int w[16];
            #pragma unroll
            for (int k = 0; k < 4; ++k) {
                const uint4 a = *(const uint4*)&uT[swz(rE, cE + k * 4)];
                w[k * 4 + 0] = a.x; w[k * 4 + 1] = a.y; w[k * 4 + 2] = a.z; w[k * 4 + 3] = a.w;
            }
            #pragma unroll
            for (int h8 = 0; h8 < 2; ++h8) {
                const ushort8 hh = *(const ushort8*)&h_hi[off + h8 * 8];
                const ushort8 ll = *(const ushort8*)&h_lo[off + h8 * 8];
                const float4 w0 = ld4(&Wout[cE + h8 * 8]);
                const float4 w1 = ld4(&Wout[cE + h8 * 8 + 4]);
                float o[8];
                #pragma unroll
                for (int j = 0; j < 8; ++j)
                    o[j] = fmaxf(__uint_as_float(w[h8 * 8 + j]) + bf2f(hh[j]) + bf2f(ll[j]), 0.f);
                accv += o[0] * w0.x + o[1] * w0.y + o[2] * w0.z + o[3] * w0.w;
                accv += o[4] * w1.x + o[5] * w1.y + o[6] * w1.z + o[7] * w1.w;
            }
        }
        accv += __shfl_xor(accv, 1);
        accv += __shfl_xor(accv, 2);
        accv += __shfl_xor(accv, 4);
        if ((lane & 7) == 0 && rowE < N) outv[rowE] = accv + bout[0];
    } else if (rowE < N) {
        const int off = rowE * D + cE;
        unsigned int w[16];
        #pragma unroll
        for (int k = 0; k < 4; ++k) {
            const uint4 a = *(const uint4*)&uT[swz(rE, cE + k * 4)];
            w[k * 4 + 0] = a.x; w[k * 4 + 1] = a.y; w[k * 4 + 2] = a.z; w[k * 4 + 3] = a.w;
        }
        #pragma unroll
        for (int h8 = 0; h8 < 2; ++h8) {
            const ushort8 hh = *(const ushort8*)&h_hi[off + h8 * 8];
            const ushort8 ll = *(const ushort8*)&h_lo[off + h8 * 8];
            ushort8 oh, ol;
            #pragma unroll
            for (int j = 0; j < 8; ++j) {
                const float o = fmaxf(__uint_as_float(w[h8 * 8 + j]) + bf2f(hh[j]) + bf2f(ll[j]), 0.f);
                const unsigned short h = f2bf(o);
                oh[j] = h;
                ol[j] = f2bf(o - bf2f(h));
            }
            *(ushort8*)&out_hi[off + h8 * 8] = oh;
            *(ushort8*)&out_lo[off + h8 * 8] = ol;
        }
    }
}

extern "C" void kernel_launch(void* const* d_in, const int* in_sizes, int n_in,
                              void* d_out, int out_size, void* d_ws, size_t ws_size,
                              hipStream_t stream)
{
    const float* x     = (const float*)d_in[0];
    const int*   ei    = (const int*)  d_in[1];
    const int*   attr  = (const int*)  d_in[2];
    const float* emb   = (const float*)d_in[3];
    const float* Win   = (const float*)d_in[4];
    const float* b_in  = (const float*)d_in[5];
    const float* W1_0  = (const float*)d_in[6];
    const float* b1_0  = (const float*)d_in[7];
    const float* W2_0  = (const float*)d_in[8];
    const float* b2_0  = (const float*)d_in[9];
    const float* W1_1  = (const float*)d_in[10];
    const float* b1_1  = (const float*)d_in[11];
    const float* W2_1  = (const float*)d_in[12];
    const float* b2_1  = (const float*)d_in[13];
    const float* Wout  = (const float*)d_in[14];
    const float* b_out = (const float*)d_in[15];
    float* out = (float*)d_out;

    const int N = NN;
    const int E = in_sizes[2];
    const int* srcp = ei;
    const int* dstp = ei + E;
    const int nbins = (N + 255) >> 8;
    const int eblocks = (E + CHUNK - 1) / CHUNK;

    // persistent workspace
    unsigned short* h_hi = (unsigned short*)d_ws;        // N*D ushort   (buffer A hi)
    unsigned short* h_lo = h_hi + (size_t)N * D;         // N*D ushort   (buffer A lo)
    float* aggspace = (float*)(h_lo + (size_t)N * D);    // N*D float: CSR scratch, then buffer B
    int*   rowptr = (int*)(aggspace + (size_t)N * D);    // N
    int*   epack  = rowptr + N;                          // E
    unsigned short* wp = (unsigned short*)(epack + E);   // 5*2*D*D
    unsigned short* Whi[5], *Wlo[5];
    for (int i = 0; i < 5; ++i) {
        Whi[i] = wp + (size_t)i * 2 * D * D;
        Wlo[i] = Whi[i] + D * D;
    }
    unsigned int* embp = (unsigned int*)(wp + 5 * 2 * D * D);  // 100*64 uint
    // CSR-build scratch aliased into aggspace (dead before gine_fused<false> writes)
    int2* binned    = (int2*)aggspace;                    // E
    int*  blkcnt    = (int*)(binned + E);                 // eblocks*BCSTRIDE
    int*  binTotal  = blkcnt + eblocks * BCSTRIDE;        // nbins
    int*  binStart  = binTotal + BCSTRIDE;                // nbins+1
    int*  binCursor = binStart + BCSTRIDE;                // nbins
    // double-buffered h: buffer B in aggspace (N*D*4 B == 2 * N*D*2 B)
    unsigned short* hB_hi = (unsigned short*)aggspace;    // N*D ushort
    unsigned short* hB_lo = hB_hi + (size_t)N * D;        // N*D ushort

    const int fgrid = (N + 63) / 64;                      // 1563 tiles
    const int sgrid = (5 * D * D + 6400 + BCSTRIDE + 255) / 256;

    // gemm_in tile slices overlapped with CSR stages
    const int G1 = 200;
    const int G2 = 700;
    const int G3 = fgrid - G1 - G2;                       // 663

    // ---- fused setup: W/emb prepack + binTotal zero ----
    setup_all<<<sgrid, dim3(256), 0, stream>>>(Win, W1_0, W2_0, W1_1, W2_1, wp, emb, embp, binTotal);

    // ---- CSR build overlapped with gemm_in slices (512-thr blocks) ----
    fuse_count_gemm<<<eblocks + G1, dim3(512), 0, stream>>>(
        dstp, blkcnt, binTotal, E, nbins, eblocks,
        x, Whi[0], Wlo[0], b_in, h_hi, h_lo, N, 0);
    bin_scan<<<1, 512, 0, stream>>>(binTotal, binStart, binCursor, nbins);
    fuse_scatter_gemm<<<eblocks + G2, dim3(512), 0, stream>>>(
        srcp, dstp, attr, blkcnt, binCursor, binned, E, nbins, eblocks,
        x, Whi[0], Wlo[0], b_in, h_hi, h_lo, N, G1);
    fuse_build_gemm<<<nbins + G3, dim3(512), 0, stream>>>(
        binned, binStart, rowptr, epack, nbins,
        x, Whi[0], Wlo[0], b_in, h_hi, h_lo, N, G1 + G2);

    // ---- layer 0: gather+MLP fused, h(A) -> hB ----
    gine_fused<false><<<fgrid, dim3(512), 0, stream>>>(
        h_hi, h_lo, rowptr, epack, embp,
        Whi[1], Wlo[1], b1_0, Whi[2], Wlo[2], b2_0,
        hB_hi, hB_lo, nullptr, nullptr, nullptr, N);

    // ---- layer 1 + fused output projection: hB -> out ----
    gine_fused<true><<<fgrid, dim3(512), 0, stream>>>(
        hB_hi, hB_lo, rowptr, epack, embp,
        Whi[3], Wlo[3], b1_1, Whi[4], Wlo[4], b2_1,
        nullptr, nullptr, Wout, b_out, out, N);
}